// Round 1
// baseline (660.958 us; speedup 1.0000x reference)
//
#include <hip/hip_runtime.h>
#include <hip/hip_bf16.h>

typedef __hip_bfloat16 bf16;
typedef unsigned short ushort_t;
typedef __attribute__((ext_vector_type(8))) short short8;
typedef __attribute__((ext_vector_type(4))) float float4v;

#define BATCH 4
#define HH 512
#define WW 512

// transposed-weight stash offsets (bf16 elems, at head of d_out; patches_k overwrites LAST)
#define WO_L0 0        // conv0 tap-packed [tl(4)][g(3)][o(32)][c(8)] = 3072
#define WO_L1 3072     // [ch][tap][32][32] = 9216
#define WO_L2 12288    // [ch][tap][64][32] = 18432
#define WO_L3 30720    // [ch2][tap][64][32] = 36864
#define WO_L4P 67584   // phase [ph4][ch2][tap][64][32] = 147456
#define WO_L5 215040   // [ch2][tap][32][32] = 18432
#define WO_L6P 233472  // phase [ph4][ch1][tap][32][32] = 36864
#define WO_L7 270336   // [ch][tap][16][32] = 4608

__device__ __forceinline__ ushort_t f2bfu(float f) {
  __hip_bfloat16 h = __float2bfloat16(f);
  union { __hip_bfloat16 h; ushort_t u; } c;
  c.h = h;
  return c.u;
}

// async global->LDS DMA, 16 B per lane; LDS dest = wave-uniform base + lane*16
__device__ __forceinline__ void dma16(void* lds, const void* g) {
  __builtin_amdgcn_global_load_lds(
      (const __attribute__((address_space(1))) unsigned int*)g,
      (__attribute__((address_space(3))) unsigned int*)lds, 16, 0, 0);
}

// bilinear x2 (half-pixel) row kernel: R[dy][r][u] = upw(r+dy, u),
// weight of src[i-1+u] in up[2i+dy-1+r].
__device__ __forceinline__ float upw(int k, int u) {
  int lo = k >> 1;
  float a = (k & 1) ? 0.25f : 0.75f;
  float b = (k & 1) ? 0.75f : 0.25f;
  return (u == lo) ? a : (u == lo + 1) ? b : 0.0f;
}

// ---------------------------------------------------------------------------
// Weight prep. Jobs:
//  0        : conv0 tap-packed  [tl][g][o][c8]  (k = tl*8+c, tap = g*4+tl)
//  4, 6     : phase-folded upsample+conv weights [ph][ch][tap][OP][32]
//  1,2,3,5,7: standard per-chunk [ch][tap][OP][32]
// ---------------------------------------------------------------------------
struct WP { const float* w[8]; };

__global__ __launch_bounds__(256) void prep_w(WP wp, bf16* __restrict__ dst) {
  const int job = blockIdx.y;
  const int e = blockIdx.x * 256 + threadIdx.x;
  if (job == 0) {
    if (e >= 3072) return;
    int c = e & 7;
    int o = (e >> 3) & 31;
    int g = (e >> 8) % 3;
    int tl = (e >> 8) / 3;
    int tap = g * 4 + tl;
    float v = 0.0f;
    if (tap < 9 && c < 3) v = wp.w[0][(o * 3 + c) * 9 + tap];
    dst[WO_L0 + e] = __float2bfloat16(v);
    return;
  }
  if (job == 4 || job == 6) {
    const int O = (job == 4) ? 64 : 32;
    const int I = O;
    const int NCH = I >> 5;
    const int n = 4 * NCH * 9 * O * 32;
    if (e >= n) return;
    int ic = e & 31;
    int o = (e >> 5) % O;
    int tap = (e / (32 * O)) % 9;
    int ch = (e / (9 * 32 * O)) % NCH;
    int ph = e / (NCH * 9 * 32 * O);
    int i = ch * 32 + ic;
    int u = tap / 3, v2 = tap - u * 3;
    int dy = ph >> 1, dx = ph & 1;
    const float* w = wp.w[job];
    float acc = 0.0f;
#pragma unroll
    for (int r = 0; r < 3; ++r) {
      float ry = upw(r + dy, u);
#pragma unroll
      for (int s = 0; s < 3; ++s)
        acc += w[(o * I + i) * 9 + r * 3 + s] * ry * upw(s + dx, v2);
    }
    dst[((job == 4) ? WO_L4P : WO_L6P) + e] = __float2bfloat16(acc);
    return;
  }
  int O, I, OP, off;
  const float* w;
  if (job == 1)      { O = 32; I = 32; OP = 32; off = WO_L1; w = wp.w[1]; }
  else if (job == 2) { O = 64; I = 32; OP = 64; off = WO_L2; w = wp.w[2]; }
  else if (job == 3) { O = 64; I = 64; OP = 64; off = WO_L3; w = wp.w[3]; }
  else if (job == 5) { O = 32; I = 64; OP = 32; off = WO_L5; w = wp.w[5]; }
  else               { O = 2;  I = 32; OP = 16; off = WO_L7; w = wp.w[7]; }
  const int NCH = I >> 5;
  const int n = NCH * 9 * OP * 32;
  if (e >= n) return;
  int ic = e & 31;
  int o = (e >> 5) % OP;
  int tap = (e / (32 * OP)) % 9;
  int ch = e / (9 * 32 * OP);
  int i = ch * 32 + ic;
  float v = 0.0f;
  if (o < O) v = w[(o * I + i) * 9 + tap];
  dst[off + e] = __float2bfloat16(v);
}

// ---------------------------------------------------------------------------
// pack_x: NCHW f32 (3ch) -> NHWC-8 bf16 (ch 3..7 zero)
// ---------------------------------------------------------------------------
__global__ __launch_bounds__(256) void pack_x(const float* __restrict__ x,
                                              bf16* __restrict__ xp) {
  int i = blockIdx.x * 256 + threadIdx.x;
  if (i >= BATCH * HH * WW) return;
  int b = i / (HH * WW);
  int px = i - b * (HH * WW);
  union { uint4 v; ushort_t s[8]; } o;
  o.v = make_uint4(0, 0, 0, 0);
  const float* p = x + (long)b * 3 * HH * WW + px;
  o.s[0] = f2bfu(p[0]);
  o.s[1] = f2bfu(p[HH * WW]);
  o.s[2] = f2bfu(p[2 * HH * WW]);
  *(uint4*)&xp[(long)i * 8] = o.v;
}

// ---------------------------------------------------------------------------
// conv0: tap-packed K (4 taps x 8ch = K32). 3 MFMA groups instead of 9 taps.
// in_lds [324][8] (16B/px, conflict-free); w_lds [tl][g][o][c8].
// ---------------------------------------------------------------------------
__global__ __launch_bounds__(256) void conv0_k(
    const bf16* __restrict__ xp, const bf16* __restrict__ wt,
    const float* __restrict__ bias, bf16* __restrict__ out) {
  __shared__ alignas(16) bf16 in_lds[324 * 8];
  __shared__ alignas(16) bf16 w_lds[3072];
  const int tid = threadIdx.x;
  const int lane = tid & 63;
  const int wid = tid >> 6;
  const int lm = lane & 15;
  const int quad = lane >> 4;
  const int x0 = blockIdx.x * 16, y0 = blockIdx.y * 16;
  const int b = blockIdx.z;

#pragma unroll
  for (int k = 0; k < 2; ++k) {
    int u = tid + k * 256;
    if (u < 324) {
      int hy = u / 18, hx = u - hy * 18;
      int gy = y0 - 1 + hy, gx = x0 - 1 + hx;
      uint4 v = make_uint4(0, 0, 0, 0);
      if (gy >= 0 && gy < HH && gx >= 0 && gx < WW)
        v = *(const uint4*)(xp + (((long)b * HH + gy) * WW + gx) * 8);
      *(uint4*)&in_lds[u * 8] = v;
    }
  }
#pragma unroll
  for (int k = 0; k < 2; ++k) {
    int u = tid + k * 256;
    if (u < 384) *(uint4*)&w_lds[u * 8] = *(const uint4*)(wt + u * 8);
  }
  __syncthreads();

  float4v acc[2][4];
#pragma unroll
  for (int mt = 0; mt < 2; ++mt) {
    float4v bv = *(const float4v*)(bias + mt * 16 + quad * 4);
#pragma unroll
    for (int nt = 0; nt < 4; ++nt) acc[mt][nt] = bv;
  }

#pragma unroll
  for (int g = 0; g < 3; ++g) {
    int tap = g * 4 + quad;
    if (tap > 8) tap = 8;  // clamped taps have zero A-weights
    int r = (tap * 11) >> 5;
    int s = tap - r * 3;
    short8 afrag[2], bfrag[4];
#pragma unroll
    for (int mt = 0; mt < 2; ++mt)
      afrag[mt] = *(const short8*)&w_lds[quad * 768 + (g * 32 + mt * 16 + lm) * 8];
#pragma unroll
    for (int nt = 0; nt < 4; ++nt) {
      int py = 4 * wid + nt;
      bfrag[nt] = *(const short8*)&in_lds[((py + r) * 18 + lm + s) * 8];
    }
#pragma unroll
    for (int mt = 0; mt < 2; ++mt)
#pragma unroll
      for (int nt = 0; nt < 4; ++nt)
        acc[mt][nt] = __builtin_amdgcn_mfma_f32_16x16x32_bf16(
            afrag[mt], bfrag[nt], acc[mt][nt], 0, 0, 0);
  }

#pragma unroll
  for (int mt = 0; mt < 2; ++mt)
#pragma unroll
    for (int nt = 0; nt < 4; ++nt) {
      int gy = y0 + 4 * wid + nt, gx = x0 + lm;
      union { uint2 v; ushort_t s2[4]; } pk;
#pragma unroll
      for (int r2 = 0; r2 < 4; ++r2) pk.s2[r2] = f2bfu(fmaxf(acc[mt][nt][r2], 0.0f));
      *(uint2*)&out[(((long)b * HH + gy) * WW + gx) * 32 + mt * 16 + quad * 4] = pk.v;
    }
}

// ---------------------------------------------------------------------------
// Implicit-GEMM 3x3 conv (pad 1), NHWC bf16, same-res input only.
// OUT_MODE: 0 = NHWC bf16 (+relu); 2 = flow NCHW f32 (tanh) + fused deformed;
//           3 = NHWC bf16, fused relu + 2x2 maxpool.
// Weights: per-chunk contiguous [ch][tap][COUT][32] -> staged via DMA.
// ---------------------------------------------------------------------------
template <int CIN, int COUT, int COUTR, int OUT_MODE>
__global__ __launch_bounds__(256) void conv_mfma(
    const bf16* __restrict__ in, const bf16* __restrict__ wt,
    const float* __restrict__ bias, void* __restrict__ out_, int H, int W,
    const float* __restrict__ temp, float* __restrict__ def) {
  constexpr int MT = COUT / 16;
  constexpr int CK = 32;
  __shared__ alignas(16) bf16 in_lds[324 * CK];
  __shared__ alignas(16) bf16 w_lds[9 * COUT * CK];
  const int tid = threadIdx.x;
  const int lane = tid & 63;
  const int wid = tid >> 6;
  const int lm = lane & 15;
  const int quad = lane >> 4;
  const int x0 = blockIdx.x * 16;
  const int y0 = blockIdx.y * 16;
  const int b = blockIdx.z;

  float4v acc[MT][4];
#pragma unroll
  for (int mt = 0; mt < MT; ++mt) {
    float4v bv;
    if constexpr (COUTR == COUT) {
      bv = *(const float4v*)(bias + mt * 16 + quad * 4);
    } else {
#pragma unroll
      for (int r = 0; r < 4; ++r) {
        int co = mt * 16 + quad * 4 + r;
        bv[r] = (co < COUTR) ? bias[co] : 0.0f;
      }
    }
#pragma unroll
    for (int nt = 0; nt < 4; ++nt) acc[mt][nt] = bv;
  }

  const bool interior =
      (x0 >= 1) && (x0 + 16 <= W - 1) && (y0 >= 1) && (y0 + 16 <= H - 1);
  for (int c0 = 0; c0 < CIN; c0 += CK) {
    if (interior) {
      for (int r = wid; r < 18; r += 4) {
        int gy = y0 - 1 + r;
        const bf16* gsrc = in + (((long)b * H + gy) * W + x0) * CIN + c0 +
                           (lane >> 2) * CIN + (lane & 3) * 8;
        dma16(&in_lds[(r * 18 + 1) * CK], gsrc);
      }
      if (tid < 144) {
        int r = tid >> 3;
        int side = (tid >> 2) & 1;
        int seg = tid & 3;
        int gx = side ? (x0 + 16) : (x0 - 1);
        int gy = y0 - 1 + r;
        uint4 v = *(const uint4*)(in + (((long)b * H + gy) * W + gx) * CIN +
                                  c0 + seg * 8);
        *(uint4*)&in_lds[(r * 18 + (side ? 17 : 0)) * CK + seg * 8] = v;
      }
    } else {
      for (int u = tid; u < 324 * 4; u += 256) {
        int px = u >> 2;
        int seg = u & 3;
        int hy = px / 18, hx = px - hy * 18;
        int gy = y0 - 1 + hy, gx = x0 - 1 + hx;
        uint4 v = make_uint4(0, 0, 0, 0);
        if (gy >= 0 && gy < H && gx >= 0 && gx < W)
          v = *(const uint4*)(in + (((long)b * H + gy) * W + gx) * CIN + c0 +
                              seg * 8);
        *(uint4*)&in_lds[px * CK + seg * 8] = v;
      }
    }
    {
      const char* wsrc = (const char*)(wt + (size_t)(c0 >> 5) * 9 * COUT * CK);
      constexpr int WCH = 9 * COUT * CK * 2 / 1024;
      for (int j = wid; j < WCH; j += 4)
        dma16((char*)w_lds + j * 1024, wsrc + j * 1024 + lane * 16);
    }
    __syncthreads();

#pragma unroll
    for (int tap = 0; tap < 9; ++tap) {
      const int r = tap / 3, s = tap - r * 3;
      short8 afrag[MT], bfrag[4];
#pragma unroll
      for (int mt = 0; mt < MT; ++mt)
        afrag[mt] =
            *(const short8*)&w_lds[(tap * COUT + mt * 16 + lm) * CK + quad * 8];
#pragma unroll
      for (int nt = 0; nt < 4; ++nt) {
        int py = 4 * wid + nt;
        bfrag[nt] =
            *(const short8*)&in_lds[((py + r) * 18 + lm + s) * CK + quad * 8];
      }
#pragma unroll
      for (int mt = 0; mt < MT; ++mt)
#pragma unroll
        for (int nt = 0; nt < 4; ++nt)
          acc[mt][nt] = __builtin_amdgcn_mfma_f32_16x16x32_bf16(
              afrag[mt], bfrag[nt], acc[mt][nt], 0, 0, 0);
    }
    __syncthreads();
  }

  if constexpr (OUT_MODE == 3) {
    bf16* out = (bf16*)out_;
    const int Ho = H >> 1, Wo = W >> 1;
#pragma unroll
    for (int mt = 0; mt < MT; ++mt) {
#pragma unroll
      for (int g = 0; g < 2; ++g) {
        float4v m;
#pragma unroll
        for (int r = 0; r < 4; ++r)
          m[r] = fmaxf(fmaxf(acc[mt][2 * g][r], acc[mt][2 * g + 1][r]), 0.0f);
#pragma unroll
        for (int r = 0; r < 4; ++r) m[r] = fmaxf(m[r], __shfl_xor(m[r], 1, 64));
        if ((lm & 1) == 0) {
          int pyo = (y0 >> 1) + 2 * wid + g;
          int pxo = (x0 >> 1) + (lm >> 1);
          union { uint2 v; ushort_t s[4]; } pk;
#pragma unroll
          for (int r = 0; r < 4; ++r) pk.s[r] = f2bfu(m[r]);
          *(uint2*)&out[(((long)b * Ho + pyo) * Wo + pxo) * COUT + mt * 16 +
                        quad * 4] = pk.v;
        }
      }
    }
  } else {
#pragma unroll
    for (int mt = 0; mt < MT; ++mt) {
#pragma unroll
      for (int nt = 0; nt < 4; ++nt) {
        int gy = y0 + 4 * wid + nt;
        int gx = x0 + lm;
        float4v v = acc[mt][nt];
        if constexpr (OUT_MODE == 0) {
          bf16* out = (bf16*)out_;
          union { uint2 v; ushort_t s[4]; } pk;
#pragma unroll
          for (int r = 0; r < 4; ++r) pk.s[r] = f2bfu(fmaxf(v[r], 0.0f));
          *(uint2*)&out[(((long)b * H + gy) * W + gx) * COUT + mt * 16 +
                        quad * 4] = pk.v;
        } else {
          float* out = (float*)out_;
          if (quad == 0) {
            float fx = tanhf(v[0]);
            float fy = tanhf(v[1]);
            out[(((long)b * 2 + 0) * H + gy) * (long)W + gx] = fx;
            out[(((long)b * 2 + 1) * H + gy) * (long)W + gx] = fy;
            float T = temp[0];
            float2 d;
            d.x = -1.0f + gx * (2.0f / 511.0f) + fx * T;
            d.y = -1.0f + gy * (2.0f / 511.0f) + fy * T;
            *(float2*)&def[(((long)b * HH + gy) * WW + gx) * 2] = d;
          }
        }
      }
    }
  }
}

// ---------------------------------------------------------------------------
// conv_up: fused (x2 bilinear upsample -> 3x3 conv -> relu) as 4 phase-convs
// on the HALF-res grid with prep-folded phase weights. Block covers 16x16 src
// px = 32x32 output px. Exact except the 1-px output ring (fixed by ring_fix).
// Edge blocks stage the src halo with CLAMP (resize edge semantics).
// ---------------------------------------------------------------------------
template <int CIN, int COUT>
__global__ __launch_bounds__(256) void conv_up(
    const bf16* __restrict__ in, const bf16* __restrict__ wt,
    const float* __restrict__ bias, bf16* __restrict__ out, int Ho, int Wo) {
  constexpr int MT = COUT / 16;
  constexpr int CK = 32;
  __shared__ alignas(16) bf16 in_lds[324 * CK];
  __shared__ alignas(16) bf16 w_lds[9 * COUT * CK];
  const int tid = threadIdx.x;
  const int lane = tid & 63;
  const int wid = tid >> 6;
  const int lm = lane & 15;
  const int quad = lane >> 4;
  const int Hs = Ho >> 1, Ws = Wo >> 1;
  const int NB = Wo >> 5;
  const int bx = blockIdx.x, by = blockIdx.y;
  const int xs0 = bx * 16, ys0 = by * 16;
  const int b = blockIdx.z;
  const bool interior = (bx >= 1) && (bx < NB - 1) && (by >= 1) && (by < NB - 1);

  for (int ph = 0; ph < 4; ++ph) {
    float4v acc[MT][4];
#pragma unroll
    for (int mt = 0; mt < MT; ++mt) {
      float4v bv = *(const float4v*)(bias + mt * 16 + quad * 4);
#pragma unroll
      for (int nt = 0; nt < 4; ++nt) acc[mt][nt] = bv;
    }
    for (int c0 = 0; c0 < CIN; c0 += CK) {
      if (ph == 0 || CIN > CK) {
        if (interior) {
          for (int r = wid; r < 18; r += 4) {
            int gy = ys0 - 1 + r;
            const bf16* gsrc = in + (((long)b * Hs + gy) * Ws + xs0) * CIN +
                               c0 + (lane >> 2) * CIN + (lane & 3) * 8;
            dma16(&in_lds[(r * 18 + 1) * CK], gsrc);
          }
          if (tid < 144) {
            int r = tid >> 3;
            int side = (tid >> 2) & 1;
            int seg = tid & 3;
            int gx = side ? (xs0 + 16) : (xs0 - 1);
            int gy = ys0 - 1 + r;
            uint4 v = *(const uint4*)(in + (((long)b * Hs + gy) * Ws + gx) * CIN +
                                      c0 + seg * 8);
            *(uint4*)&in_lds[(r * 18 + (side ? 17 : 0)) * CK + seg * 8] = v;
          }
        } else {
          for (int u = tid; u < 324 * 4; u += 256) {
            int px = u >> 2;
            int seg = u & 3;
            int hy = px / 18, hx = px - hy * 18;
            int sy = min(max(ys0 - 1 + hy, 0), Hs - 1);
            int sx = min(max(xs0 - 1 + hx, 0), Ws - 1);
            uint4 v = *(const uint4*)(in + (((long)b * Hs + sy) * Ws + sx) * CIN +
                                      c0 + seg * 8);
            *(uint4*)&in_lds[px * CK + seg * 8] = v;
          }
        }
      }
      {
        const char* wsrc = (const char*)(wt + (size_t)(ph * (CIN / CK) + (c0 >> 5)) *
                                                  9 * COUT * CK);
        constexpr int WCH = 9 * COUT * CK * 2 / 1024;
        for (int j = wid; j < WCH; j += 4)
          dma16((char*)w_lds + j * 1024, wsrc + j * 1024 + lane * 16);
      }
      __syncthreads();
#pragma unroll
      for (int tap = 0; tap < 9; ++tap) {
        const int r = tap / 3, s = tap - r * 3;
        short8 afrag[MT], bfrag[4];
#pragma unroll
        for (int mt = 0; mt < MT; ++mt)
          afrag[mt] =
              *(const short8*)&w_lds[(tap * COUT + mt * 16 + lm) * CK + quad * 8];
#pragma unroll
        for (int nt = 0; nt < 4; ++nt) {
          int py = 4 * wid + nt;
          bfrag[nt] =
              *(const short8*)&in_lds[((py + r) * 18 + lm + s) * CK + quad * 8];
        }
#pragma unroll
        for (int mt = 0; mt < MT; ++mt)
#pragma unroll
          for (int nt = 0; nt < 4; ++nt)
            acc[mt][nt] = __builtin_amdgcn_mfma_f32_16x16x32_bf16(
                afrag[mt], bfrag[nt], acc[mt][nt], 0, 0, 0);
      }
      __syncthreads();
    }
    const int dy = ph >> 1, dx = ph & 1;
#pragma unroll
    for (int mt = 0; mt < MT; ++mt)
#pragma unroll
      for (int nt = 0; nt < 4; ++nt) {
        int gy = 2 * (ys0 + 4 * wid + nt) + dy;
        int gx = 2 * (xs0 + lm) + dx;
        union { uint2 v; ushort_t s2[4]; } pk;
#pragma unroll
        for (int r2 = 0; r2 < 4; ++r2)
          pk.s2[r2] = f2bfu(fmaxf(acc[mt][nt][r2], 0.0f));
        *(uint2*)&out[(((long)b * Ho + gy) * Wo + gx) * COUT + mt * 16 +
                      quad * 4] = pk.v;
      }
  }
}

// ---------------------------------------------------------------------------
// ring_fix: exact recompute (orig f32 weights, explicit upsample, zero-pad
// conv) of the 1-px output ring that conv_up's phase decomposition gets wrong.
// One thread per (ring px, 8-chan group).
// ---------------------------------------------------------------------------
template <int CIN, int COUT>
__global__ __launch_bounds__(256) void ring_fix(
    const bf16* __restrict__ src, const float* __restrict__ wf,
    const float* __restrict__ bias, bf16* __restrict__ out, int Ho, int Wo) {
  constexpr int OG = COUT / 8;
  int i = blockIdx.x * 256 + threadIdx.x;
  int ring = 2 * Wo + 2 * (Ho - 2);
  int total = BATCH * ring * OG;
  if (i >= total) return;
  int og = i % OG;
  int pxi = i / OG;
  int b = pxi / ring;
  int t = pxi - b * ring;
  int gy, gx;
  if (t < Wo) { gy = 0; gx = t; }
  else if (t < 2 * Wo) { gy = Ho - 1; gx = t - Wo; }
  else { int u = t - 2 * Wo; gy = 1 + (u >> 1); gx = (u & 1) ? (Wo - 1) : 0; }
  int Hs = Ho >> 1, Ws = Wo >> 1;
  float acc[8];
#pragma unroll
  for (int j = 0; j < 8; ++j) acc[j] = bias[og * 8 + j];
  for (int r = 0; r < 3; ++r)
    for (int s = 0; s < 3; ++s) {
      int uy = gy - 1 + r, ux = gx - 1 + s;
      if (uy < 0 || uy >= Ho || ux < 0 || ux >= Wo) continue;  // zero pad
      int ys = (uy >> 1) - ((uy & 1) ? 0 : 1);
      int xs = (ux >> 1) - ((ux & 1) ? 0 : 1);
      float wy = (uy & 1) ? 0.25f : 0.75f;
      float wx = (ux & 1) ? 0.25f : 0.75f;
      int y0c = max(ys, 0), y1c = min(ys + 1, Hs - 1);
      int x0c = max(xs, 0), x1c = min(xs + 1, Ws - 1);
      const bf16* p00 = src + (((long)b * Hs + y0c) * Ws + x0c) * CIN;
      const bf16* p01 = src + (((long)b * Hs + y0c) * Ws + x1c) * CIN;
      const bf16* p10 = src + (((long)b * Hs + y1c) * Ws + x0c) * CIN;
      const bf16* p11 = src + (((long)b * Hs + y1c) * Ws + x1c) * CIN;
      const float* wtap = wf + r * 3 + s;
#pragma unroll 8
      for (int ci = 0; ci < CIN; ++ci) {
        float up =
            (1.0f - wy) * ((1.0f - wx) * __bfloat162float(p00[ci]) +
                           wx * __bfloat162float(p01[ci])) +
            wy * ((1.0f - wx) * __bfloat162float(p10[ci]) +
                  wx * __bfloat162float(p11[ci]));
#pragma unroll
        for (int j = 0; j < 8; ++j)
          acc[j] += wtap[(((og * 8 + j) * CIN) + ci) * 9] * up;
      }
    }
  union { uint4 v; ushort_t us[8]; } pk;
#pragma unroll
  for (int j = 0; j < 8; ++j) pk.us[j] = f2bfu(fmaxf(acc[j], 0.0f));
  *(uint4*)&out[(((long)b * Ho + gy) * Wo + gx) * COUT + og * 8] = pk.v;
}

// ---------------------------------------------------------------------------
// patches: grid_sample bilinear, zeros padding -> out [B,256,3,64,64]
// ---------------------------------------------------------------------------
__global__ __launch_bounds__(256) void patches_k(const float* __restrict__ x,
                                                 const float* __restrict__ def,
                                                 float* __restrict__ out) {
  int i = blockIdx.x * 256 + threadIdx.x;
  int pj = i & 63;
  int t = i >> 6;
  int pi = t & 63;
  t >>= 6;
  int n = t & 255;
  int b = t >> 8;
  if (b >= BATCH) return;
  int hi = n >> 4, wi = n & 15;
  const float* dptr = def + (((long)b * HH + hi * 32) * WW + wi * 32) * 2;
  float cx = dptr[0], cy = dptr[1];
  float pgx = cx + (-1.0f + pj * (2.0f / 63.0f)) * 0.125f;
  float pgy = cy + (-1.0f + pi * (2.0f / 63.0f)) * 0.125f;
  float ix = ((pgx + 1.0f) * 512.0f - 1.0f) * 0.5f;
  float iy = ((pgy + 1.0f) * 512.0f - 1.0f) * 0.5f;
  float fx0 = floorf(ix), fy0 = floorf(iy);
  float wx1 = ix - fx0, wy1 = iy - fy0;
  int x0 = (int)fx0, y0 = (int)fy0;
  int x1 = x0 + 1, y1 = y0 + 1;
  bool vx0 = (x0 >= 0) && (x0 <= 511), vx1 = (x1 >= 0) && (x1 <= 511);
  bool vy0 = (y0 >= 0) && (y0 <= 511), vy1 = (y1 >= 0) && (y1 <= 511);
  int cx0 = min(max(x0, 0), 511), cx1 = min(max(x1, 0), 511);
  int cy0 = min(max(y0, 0), 511), cy1 = min(max(y1, 0), 511);
  float w00 = (1.0f - wx1) * (1.0f - wy1) * ((vx0 && vy0) ? 1.0f : 0.0f);
  float w01 = wx1 * (1.0f - wy1) * ((vx1 && vy0) ? 1.0f : 0.0f);
  float w10 = (1.0f - wx1) * wy1 * ((vx0 && vy1) ? 1.0f : 0.0f);
  float w11 = wx1 * wy1 * ((vx1 && vy1) ? 1.0f : 0.0f);
#pragma unroll
  for (int c = 0; c < 3; ++c) {
    const float* img = x + ((long)b * 3 + c) * (HH * WW);
    float v = img[cy0 * WW + cx0] * w00 + img[cy0 * WW + cx1] * w01 +
              img[cy1 * WW + cx0] * w10 + img[cy1 * WW + cx1] * w11;
    out[(((long)b * 256 + n) * 3 + c) * 4096 + pi * 64 + pj] = v;
  }
}

// ---------------------------------------------------------------------------

extern "C" void kernel_launch(void* const* d_in, const int* in_sizes, int n_in,
                              void* d_out, int out_size, void* d_ws,
                              size_t ws_size, hipStream_t stream) {
  const float* x = (const float*)d_in[0];
  WP wp;
  const float* bs[8];
  for (int i = 0; i < 8; ++i) {
    wp.w[i] = (const float*)d_in[1 + 2 * i];
    bs[i] = (const float*)d_in[2 + 2 * i];
  }
  const float* temp = (const float*)d_in[17];

  float* out = (float*)d_out;
  float* flow = out + 12582912;  // [B,2,512,512] f32
  float* def = out + 14680064;   // [B,512,512,2] f32
  bf16* wT = (bf16*)d_out;       // weight stash; patches_k overwrites LAST

  const size_t bufElems = (size_t)BATCH * 512 * 512 * 32;
  bf16* A = (bf16*)d_ws;
  bf16* Bf = A + bufElems;
  bf16* xp = Bf + bufElems;

  prep_w<<<dim3(576, 8), 256, 0, stream>>>(wp, wT);
  pack_x<<<(BATCH * HH * WW) / 256, 256, 0, stream>>>(x, xp);

  dim3 g512(32, 32, BATCH);
  dim3 g256(16, 16, BATCH);

  // conv0 (tap-packed): xp -> A [512,512,32]
  conv0_k<<<g512, 256, 0, stream>>>(xp, wT + WO_L0, bs[0], A);
  // conv1 + relu + pool: A -> Bf [256,256,32]
  conv_mfma<32, 32, 32, 3>
      <<<g512, 256, 0, stream>>>(A, wT + WO_L1, bs[1], Bf, 512, 512, nullptr, nullptr);
  // conv2: Bf -> A [256,256,64]
  conv_mfma<32, 64, 64, 0>
      <<<g256, 256, 0, stream>>>(Bf, wT + WO_L2, bs[2], A, 256, 256, nullptr, nullptr);
  // conv3 + relu + pool: A -> Bf [128,128,64]
  conv_mfma<64, 64, 64, 3>
      <<<g256, 256, 0, stream>>>(A, wT + WO_L3, bs[3], Bf, 256, 256, nullptr, nullptr);
  // conv4 (phase-decomposed up1): Bf(128² src) -> A [256,256,64]
  conv_up<64, 64><<<dim3(8, 8, BATCH), 256, 0, stream>>>(Bf, wT + WO_L4P, bs[4], A, 256, 256);
  ring_fix<64, 64><<<128, 256, 0, stream>>>(Bf, wp.w[4], bs[4], A, 256, 256);
  // conv5: A -> Bf [256,256,32]
  conv_mfma<64, 32, 32, 0>
      <<<g256, 256, 0, stream>>>(A, wT + WO_L5, bs[5], Bf, 256, 256, nullptr, nullptr);
  // conv6 (phase-decomposed up2): Bf(256² src) -> A [512,512,32]
  conv_up<32, 32><<<dim3(16, 16, BATCH), 256, 0, stream>>>(Bf, wT + WO_L6P, bs[6], A, 512, 512);
  ring_fix<32, 32><<<128, 256, 0, stream>>>(Bf, wp.w[6], bs[6], A, 512, 512);
  // conv7 + tanh + fused deformed: A -> flow + def
  conv_mfma<32, 16, 2, 2>
      <<<g512, 256, 0, stream>>>(A, wT + WO_L7, bs[7], flow, 512, 512, temp, def);
  // patches (overwrites the wT stash)
  patches_k<<<(BATCH * 256 * 64 * 64) / 256, 256, 0, stream>>>(x, def, out);
}

// Round 2
// 356.583 us; speedup vs baseline: 1.8536x; 1.8536x over previous
//
#include <hip/hip_runtime.h>
#include <hip/hip_bf16.h>

typedef __hip_bfloat16 bf16;
typedef unsigned short ushort_t;
typedef __attribute__((ext_vector_type(8))) short short8;
typedef __attribute__((ext_vector_type(4))) float float4v;

#define BATCH 4
#define HH 512
#define WW 512

// transposed-weight stash offsets (bf16 elems, at head of d_out; patches_k overwrites LAST)
#define WO_L0 0        // conv0 tap-packed [tl(4)][g(3)][o(32)][c(8)] = 3072
#define WO_L1 3072     // [ch][tap][32][32] = 9216
#define WO_L2 12288    // [ch][tap][64][32] = 18432
#define WO_L3 30720    // [ch2][tap][64][32] = 36864
#define WO_L4P 67584   // phase [ph4][ch2][tap][64][32] = 147456
#define WO_L5 215040   // [ch2][tap][32][32] = 18432
#define WO_L6P 233472  // phase [ph4][ch1][tap][32][32] = 36864
#define WO_L7 270336   // [ch][tap][16][32] = 4608
#define WO_L4U 274944  // unfused L4 [ch2][tap][64][32] = 36864 (for conv_edge)
#define WO_L6U 311808  // unfused L6 [ch1][tap][32][32] = 9216  (for conv_edge)

__device__ __forceinline__ ushort_t f2bfu(float f) {
  __hip_bfloat16 h = __float2bfloat16(f);
  union { __hip_bfloat16 h; ushort_t u; } c;
  c.h = h;
  return c.u;
}
__device__ __forceinline__ float bfu2f(ushort_t u) {
  return __uint_as_float(((unsigned)u) << 16);
}

// async global->LDS DMA, 16 B per lane; LDS dest = wave-uniform base + lane*16
__device__ __forceinline__ void dma16(void* lds, const void* g) {
  __builtin_amdgcn_global_load_lds(
      (const __attribute__((address_space(1))) unsigned int*)g,
      (__attribute__((address_space(3))) unsigned int*)lds, 16, 0, 0);
}

// bilinear x2 (half-pixel) row kernel: weight of src[i-1+u] in up[2i+dy-1+r].
__device__ __forceinline__ float upw(int k, int u) {
  int lo = k >> 1;
  float a = (k & 1) ? 0.25f : 0.75f;
  float b = (k & 1) ? 0.75f : 0.25f;
  return (u == lo) ? a : (u == lo + 1) ? b : 0.0f;
}

// ---------------------------------------------------------------------------
// Weight prep. Jobs:
//  0        : conv0 tap-packed  [tl][g][o][c8]  (k = tl*8+c, tap = g*4+tl)
//  4, 6     : phase-folded upsample+conv weights [ph][ch][tap][OP][32]
//  1,2,3,5,7: standard per-chunk [ch][tap][OP][32]
//  8, 9     : UNFUSED L4/L6 per-chunk [ch][tap][OP][32] (for conv_edge)
// ---------------------------------------------------------------------------
struct WP { const float* w[8]; };

__global__ __launch_bounds__(256) void prep_w(WP wp, bf16* __restrict__ dst) {
  const int job = blockIdx.y;
  const int e = blockIdx.x * 256 + threadIdx.x;
  if (job == 0) {
    if (e >= 3072) return;
    int c = e & 7;
    int o = (e >> 3) & 31;
    int g = (e >> 8) % 3;
    int tl = (e >> 8) / 3;
    int tap = g * 4 + tl;
    float v = 0.0f;
    if (tap < 9 && c < 3) v = wp.w[0][(o * 3 + c) * 9 + tap];
    dst[WO_L0 + e] = __float2bfloat16(v);
    return;
  }
  if (job == 4 || job == 6) {
    const int O = (job == 4) ? 64 : 32;
    const int I = O;
    const int NCH = I >> 5;
    const int n = 4 * NCH * 9 * O * 32;
    if (e >= n) return;
    int ic = e & 31;
    int o = (e >> 5) % O;
    int tap = (e / (32 * O)) % 9;
    int ch = (e / (9 * 32 * O)) % NCH;
    int ph = e / (NCH * 9 * 32 * O);
    int i = ch * 32 + ic;
    int u = tap / 3, v2 = tap - u * 3;
    int dy = ph >> 1, dx = ph & 1;
    const float* w = wp.w[job];
    float acc = 0.0f;
#pragma unroll
    for (int r = 0; r < 3; ++r) {
      float ry = upw(r + dy, u);
#pragma unroll
      for (int s = 0; s < 3; ++s)
        acc += w[(o * I + i) * 9 + r * 3 + s] * ry * upw(s + dx, v2);
    }
    dst[((job == 4) ? WO_L4P : WO_L6P) + e] = __float2bfloat16(acc);
    return;
  }
  int O, I, OP, off;
  const float* w;
  if (job == 1)      { O = 32; I = 32; OP = 32; off = WO_L1; w = wp.w[1]; }
  else if (job == 2) { O = 64; I = 32; OP = 64; off = WO_L2; w = wp.w[2]; }
  else if (job == 3) { O = 64; I = 64; OP = 64; off = WO_L3; w = wp.w[3]; }
  else if (job == 5) { O = 32; I = 64; OP = 32; off = WO_L5; w = wp.w[5]; }
  else if (job == 7) { O = 2;  I = 32; OP = 16; off = WO_L7; w = wp.w[7]; }
  else if (job == 8) { O = 64; I = 64; OP = 64; off = WO_L4U; w = wp.w[4]; }
  else               { O = 32; I = 32; OP = 32; off = WO_L6U; w = wp.w[6]; }
  const int NCH = I >> 5;
  const int n = NCH * 9 * OP * 32;
  if (e >= n) return;
  int ic = e & 31;
  int o = (e >> 5) % OP;
  int tap = (e / (32 * OP)) % 9;
  int ch = e / (9 * 32 * OP);
  int i = ch * 32 + ic;
  float v = 0.0f;
  if (o < O) v = w[(o * I + i) * 9 + tap];
  dst[off + e] = __float2bfloat16(v);
}

// ---------------------------------------------------------------------------
// pack_x: NCHW f32 (3ch) -> NHWC-8 bf16 (ch 3..7 zero)
// ---------------------------------------------------------------------------
__global__ __launch_bounds__(256) void pack_x(const float* __restrict__ x,
                                              bf16* __restrict__ xp) {
  int i = blockIdx.x * 256 + threadIdx.x;
  if (i >= BATCH * HH * WW) return;
  int b = i / (HH * WW);
  int px = i - b * (HH * WW);
  union { uint4 v; ushort_t s[8]; } o;
  o.v = make_uint4(0, 0, 0, 0);
  const float* p = x + (long)b * 3 * HH * WW + px;
  o.s[0] = f2bfu(p[0]);
  o.s[1] = f2bfu(p[HH * WW]);
  o.s[2] = f2bfu(p[2 * HH * WW]);
  *(uint4*)&xp[(long)i * 8] = o.v;
}

// ---------------------------------------------------------------------------
// conv0: tap-packed K (4 taps x 8ch = K32). 3 MFMA groups instead of 9 taps.
// ---------------------------------------------------------------------------
__global__ __launch_bounds__(256) void conv0_k(
    const bf16* __restrict__ xp, const bf16* __restrict__ wt,
    const float* __restrict__ bias, bf16* __restrict__ out) {
  __shared__ alignas(16) bf16 in_lds[324 * 8];
  __shared__ alignas(16) bf16 w_lds[3072];
  const int tid = threadIdx.x;
  const int lane = tid & 63;
  const int wid = tid >> 6;
  const int lm = lane & 15;
  const int quad = lane >> 4;
  const int x0 = blockIdx.x * 16, y0 = blockIdx.y * 16;
  const int b = blockIdx.z;

#pragma unroll
  for (int k = 0; k < 2; ++k) {
    int u = tid + k * 256;
    if (u < 324) {
      int hy = u / 18, hx = u - hy * 18;
      int gy = y0 - 1 + hy, gx = x0 - 1 + hx;
      uint4 v = make_uint4(0, 0, 0, 0);
      if (gy >= 0 && gy < HH && gx >= 0 && gx < WW)
        v = *(const uint4*)(xp + (((long)b * HH + gy) * WW + gx) * 8);
      *(uint4*)&in_lds[u * 8] = v;
    }
  }
#pragma unroll
  for (int k = 0; k < 2; ++k) {
    int u = tid + k * 256;
    if (u < 384) *(uint4*)&w_lds[u * 8] = *(const uint4*)(wt + u * 8);
  }
  __syncthreads();

  float4v acc[2][4];
#pragma unroll
  for (int mt = 0; mt < 2; ++mt) {
    float4v bv = *(const float4v*)(bias + mt * 16 + quad * 4);
#pragma unroll
    for (int nt = 0; nt < 4; ++nt) acc[mt][nt] = bv;
  }

#pragma unroll
  for (int g = 0; g < 3; ++g) {
    int tap = g * 4 + quad;
    if (tap > 8) tap = 8;  // clamped taps have zero A-weights
    int r = (tap * 11) >> 5;
    int s = tap - r * 3;
    short8 afrag[2], bfrag[4];
#pragma unroll
    for (int mt = 0; mt < 2; ++mt)
      afrag[mt] = *(const short8*)&w_lds[quad * 768 + (g * 32 + mt * 16 + lm) * 8];
#pragma unroll
    for (int nt = 0; nt < 4; ++nt) {
      int py = 4 * wid + nt;
      bfrag[nt] = *(const short8*)&in_lds[((py + r) * 18 + lm + s) * 8];
    }
#pragma unroll
    for (int mt = 0; mt < 2; ++mt)
#pragma unroll
      for (int nt = 0; nt < 4; ++nt)
        acc[mt][nt] = __builtin_amdgcn_mfma_f32_16x16x32_bf16(
            afrag[mt], bfrag[nt], acc[mt][nt], 0, 0, 0);
  }

#pragma unroll
  for (int mt = 0; mt < 2; ++mt)
#pragma unroll
    for (int nt = 0; nt < 4; ++nt) {
      int gy = y0 + 4 * wid + nt, gx = x0 + lm;
      union { uint2 v; ushort_t s2[4]; } pk;
#pragma unroll
      for (int r2 = 0; r2 < 4; ++r2) pk.s2[r2] = f2bfu(fmaxf(acc[mt][nt][r2], 0.0f));
      *(uint2*)&out[(((long)b * HH + gy) * WW + gx) * 32 + mt * 16 + quad * 4] = pk.v;
    }
}

// ---------------------------------------------------------------------------
// Implicit-GEMM 3x3 conv (pad 1), NHWC bf16, same-res input only.
// OUT_MODE: 0 = NHWC bf16 (+relu); 2 = flow NCHW f32 (tanh) + fused deformed;
//           3 = NHWC bf16, fused relu + 2x2 maxpool.
// ---------------------------------------------------------------------------
template <int CIN, int COUT, int COUTR, int OUT_MODE>
__global__ __launch_bounds__(256) void conv_mfma(
    const bf16* __restrict__ in, const bf16* __restrict__ wt,
    const float* __restrict__ bias, void* __restrict__ out_, int H, int W,
    const float* __restrict__ temp, float* __restrict__ def) {
  constexpr int MT = COUT / 16;
  constexpr int CK = 32;
  __shared__ alignas(16) bf16 in_lds[324 * CK];
  __shared__ alignas(16) bf16 w_lds[9 * COUT * CK];
  const int tid = threadIdx.x;
  const int lane = tid & 63;
  const int wid = tid >> 6;
  const int lm = lane & 15;
  const int quad = lane >> 4;
  const int x0 = blockIdx.x * 16;
  const int y0 = blockIdx.y * 16;
  const int b = blockIdx.z;

  float4v acc[MT][4];
#pragma unroll
  for (int mt = 0; mt < MT; ++mt) {
    float4v bv;
    if constexpr (COUTR == COUT) {
      bv = *(const float4v*)(bias + mt * 16 + quad * 4);
    } else {
#pragma unroll
      for (int r = 0; r < 4; ++r) {
        int co = mt * 16 + quad * 4 + r;
        bv[r] = (co < COUTR) ? bias[co] : 0.0f;
      }
    }
#pragma unroll
    for (int nt = 0; nt < 4; ++nt) acc[mt][nt] = bv;
  }

  const bool interior =
      (x0 >= 1) && (x0 + 16 <= W - 1) && (y0 >= 1) && (y0 + 16 <= H - 1);
  for (int c0 = 0; c0 < CIN; c0 += CK) {
    if (interior) {
      for (int r = wid; r < 18; r += 4) {
        int gy = y0 - 1 + r;
        const bf16* gsrc = in + (((long)b * H + gy) * W + x0) * CIN + c0 +
                           (lane >> 2) * CIN + (lane & 3) * 8;
        dma16(&in_lds[(r * 18 + 1) * CK], gsrc);
      }
      if (tid < 144) {
        int r = tid >> 3;
        int side = (tid >> 2) & 1;
        int seg = tid & 3;
        int gx = side ? (x0 + 16) : (x0 - 1);
        int gy = y0 - 1 + r;
        uint4 v = *(const uint4*)(in + (((long)b * H + gy) * W + gx) * CIN +
                                  c0 + seg * 8);
        *(uint4*)&in_lds[(r * 18 + (side ? 17 : 0)) * CK + seg * 8] = v;
      }
    } else {
      for (int u = tid; u < 324 * 4; u += 256) {
        int px = u >> 2;
        int seg = u & 3;
        int hy = px / 18, hx = px - hy * 18;
        int gy = y0 - 1 + hy, gx = x0 - 1 + hx;
        uint4 v = make_uint4(0, 0, 0, 0);
        if (gy >= 0 && gy < H && gx >= 0 && gx < W)
          v = *(const uint4*)(in + (((long)b * H + gy) * W + gx) * CIN + c0 +
                              seg * 8);
        *(uint4*)&in_lds[px * CK + seg * 8] = v;
      }
    }
    {
      const char* wsrc = (const char*)(wt + (size_t)(c0 >> 5) * 9 * COUT * CK);
      constexpr int WCH = 9 * COUT * CK * 2 / 1024;
      for (int j = wid; j < WCH; j += 4)
        dma16((char*)w_lds + j * 1024, wsrc + j * 1024 + lane * 16);
    }
    __syncthreads();

#pragma unroll
    for (int tap = 0; tap < 9; ++tap) {
      const int r = tap / 3, s = tap - r * 3;
      short8 afrag[MT], bfrag[4];
#pragma unroll
      for (int mt = 0; mt < MT; ++mt)
        afrag[mt] =
            *(const short8*)&w_lds[(tap * COUT + mt * 16 + lm) * CK + quad * 8];
#pragma unroll
      for (int nt = 0; nt < 4; ++nt) {
        int py = 4 * wid + nt;
        bfrag[nt] =
            *(const short8*)&in_lds[((py + r) * 18 + lm + s) * CK + quad * 8];
      }
#pragma unroll
      for (int mt = 0; mt < MT; ++mt)
#pragma unroll
        for (int nt = 0; nt < 4; ++nt)
          acc[mt][nt] = __builtin_amdgcn_mfma_f32_16x16x32_bf16(
              afrag[mt], bfrag[nt], acc[mt][nt], 0, 0, 0);
    }
    __syncthreads();
  }

  if constexpr (OUT_MODE == 3) {
    bf16* out = (bf16*)out_;
    const int Ho = H >> 1, Wo = W >> 1;
#pragma unroll
    for (int mt = 0; mt < MT; ++mt) {
#pragma unroll
      for (int g = 0; g < 2; ++g) {
        float4v m;
#pragma unroll
        for (int r = 0; r < 4; ++r)
          m[r] = fmaxf(fmaxf(acc[mt][2 * g][r], acc[mt][2 * g + 1][r]), 0.0f);
#pragma unroll
        for (int r = 0; r < 4; ++r) m[r] = fmaxf(m[r], __shfl_xor(m[r], 1, 64));
        if ((lm & 1) == 0) {
          int pyo = (y0 >> 1) + 2 * wid + g;
          int pxo = (x0 >> 1) + (lm >> 1);
          union { uint2 v; ushort_t s[4]; } pk;
#pragma unroll
          for (int r = 0; r < 4; ++r) pk.s[r] = f2bfu(m[r]);
          *(uint2*)&out[(((long)b * Ho + pyo) * Wo + pxo) * COUT + mt * 16 +
                        quad * 4] = pk.v;
        }
      }
    }
  } else {
#pragma unroll
    for (int mt = 0; mt < MT; ++mt) {
#pragma unroll
      for (int nt = 0; nt < 4; ++nt) {
        int gy = y0 + 4 * wid + nt;
        int gx = x0 + lm;
        float4v v = acc[mt][nt];
        if constexpr (OUT_MODE == 0) {
          bf16* out = (bf16*)out_;
          union { uint2 v; ushort_t s[4]; } pk;
#pragma unroll
          for (int r = 0; r < 4; ++r) pk.s[r] = f2bfu(fmaxf(v[r], 0.0f));
          *(uint2*)&out[(((long)b * H + gy) * W + gx) * COUT + mt * 16 +
                        quad * 4] = pk.v;
        } else {
          float* out = (float*)out_;
          if (quad == 0) {
            float fx = tanhf(v[0]);
            float fy = tanhf(v[1]);
            out[(((long)b * 2 + 0) * H + gy) * (long)W + gx] = fx;
            out[(((long)b * 2 + 1) * H + gy) * (long)W + gx] = fy;
            float T = temp[0];
            float2 d;
            d.x = -1.0f + gx * (2.0f / 511.0f) + fx * T;
            d.y = -1.0f + gy * (2.0f / 511.0f) + fy * T;
            *(float2*)&def[(((long)b * HH + gy) * WW + gx) * 2] = d;
          }
        }
      }
    }
  }
}

// ---------------------------------------------------------------------------
// conv_up: fused (x2 bilinear upsample -> 3x3 conv -> relu) as 4 phase-convs
// on the HALF-res grid with prep-folded phase weights. Exact except the 1-px
// output ring (conv zero-pad cannot be represented in the fold) -> conv_edge
// overwrites perimeter tiles afterwards.
// ---------------------------------------------------------------------------
template <int CIN, int COUT>
__global__ __launch_bounds__(256) void conv_up(
    const bf16* __restrict__ in, const bf16* __restrict__ wt,
    const float* __restrict__ bias, bf16* __restrict__ out, int Ho, int Wo) {
  constexpr int MT = COUT / 16;
  constexpr int CK = 32;
  __shared__ alignas(16) bf16 in_lds[324 * CK];
  __shared__ alignas(16) bf16 w_lds[9 * COUT * CK];
  const int tid = threadIdx.x;
  const int lane = tid & 63;
  const int wid = tid >> 6;
  const int lm = lane & 15;
  const int quad = lane >> 4;
  const int Hs = Ho >> 1, Ws = Wo >> 1;
  const int NB = Wo >> 5;
  const int bx = blockIdx.x, by = blockIdx.y;
  const int xs0 = bx * 16, ys0 = by * 16;
  const int b = blockIdx.z;
  const bool interior = (bx >= 1) && (bx < NB - 1) && (by >= 1) && (by < NB - 1);

  for (int ph = 0; ph < 4; ++ph) {
    float4v acc[MT][4];
#pragma unroll
    for (int mt = 0; mt < MT; ++mt) {
      float4v bv = *(const float4v*)(bias + mt * 16 + quad * 4);
#pragma unroll
      for (int nt = 0; nt < 4; ++nt) acc[mt][nt] = bv;
    }
    for (int c0 = 0; c0 < CIN; c0 += CK) {
      if (ph == 0 || CIN > CK) {
        if (interior) {
          for (int r = wid; r < 18; r += 4) {
            int gy = ys0 - 1 + r;
            const bf16* gsrc = in + (((long)b * Hs + gy) * Ws + xs0) * CIN +
                               c0 + (lane >> 2) * CIN + (lane & 3) * 8;
            dma16(&in_lds[(r * 18 + 1) * CK], gsrc);
          }
          if (tid < 144) {
            int r = tid >> 3;
            int side = (tid >> 2) & 1;
            int seg = tid & 3;
            int gx = side ? (xs0 + 16) : (xs0 - 1);
            int gy = ys0 - 1 + r;
            uint4 v = *(const uint4*)(in + (((long)b * Hs + gy) * Ws + gx) * CIN +
                                      c0 + seg * 8);
            *(uint4*)&in_lds[(r * 18 + (side ? 17 : 0)) * CK + seg * 8] = v;
          }
        } else {
          for (int u = tid; u < 324 * 4; u += 256) {
            int px = u >> 2;
            int seg = u & 3;
            int hy = px / 18, hx = px - hy * 18;
            int sy = min(max(ys0 - 1 + hy, 0), Hs - 1);
            int sx = min(max(xs0 - 1 + hx, 0), Ws - 1);
            uint4 v = *(const uint4*)(in + (((long)b * Hs + sy) * Ws + sx) * CIN +
                                      c0 + seg * 8);
            *(uint4*)&in_lds[px * CK + seg * 8] = v;
          }
        }
      }
      {
        const char* wsrc = (const char*)(wt + (size_t)(ph * (CIN / CK) + (c0 >> 5)) *
                                                  9 * COUT * CK);
        constexpr int WCH = 9 * COUT * CK * 2 / 1024;
        for (int j = wid; j < WCH; j += 4)
          dma16((char*)w_lds + j * 1024, wsrc + j * 1024 + lane * 16);
      }
      __syncthreads();
#pragma unroll
      for (int tap = 0; tap < 9; ++tap) {
        const int r = tap / 3, s = tap - r * 3;
        short8 afrag[MT], bfrag[4];
#pragma unroll
        for (int mt = 0; mt < MT; ++mt)
          afrag[mt] =
              *(const short8*)&w_lds[(tap * COUT + mt * 16 + lm) * CK + quad * 8];
#pragma unroll
        for (int nt = 0; nt < 4; ++nt) {
          int py = 4 * wid + nt;
          bfrag[nt] =
              *(const short8*)&in_lds[((py + r) * 18 + lm + s) * CK + quad * 8];
        }
#pragma unroll
        for (int mt = 0; mt < MT; ++mt)
#pragma unroll
          for (int nt = 0; nt < 4; ++nt)
            acc[mt][nt] = __builtin_amdgcn_mfma_f32_16x16x32_bf16(
                afrag[mt], bfrag[nt], acc[mt][nt], 0, 0, 0);
      }
      __syncthreads();
    }
    const int dy = ph >> 1, dx = ph & 1;
#pragma unroll
    for (int mt = 0; mt < MT; ++mt)
#pragma unroll
      for (int nt = 0; nt < 4; ++nt) {
        int gy = 2 * (ys0 + 4 * wid + nt) + dy;
        int gx = 2 * (xs0 + lm) + dx;
        union { uint2 v; ushort_t s2[4]; } pk;
#pragma unroll
        for (int r2 = 0; r2 < 4; ++r2)
          pk.s2[r2] = f2bfu(fmaxf(acc[mt][nt][r2], 0.0f));
        *(uint2*)&out[(((long)b * Ho + gy) * Wo + gx) * COUT + mt * 16 +
                      quad * 4] = pk.v;
      }
  }
}

// ---------------------------------------------------------------------------
// conv_edge: exact fused upsample->conv->relu (Round-0 IN_MODE 2 semantics:
// on-the-fly bilinear staging, zero outside full-res image, clamp at src
// edges) for PERIMETER 16x16 output tiles only. Overwrites conv_up's ring.
// Weights: UNFUSED per-chunk layout via dma16.
// ---------------------------------------------------------------------------
template <int CIN, int COUT>
__global__ __launch_bounds__(256) void conv_edge(
    const bf16* __restrict__ in, const bf16* __restrict__ wt,
    const float* __restrict__ bias, bf16* __restrict__ out, int H, int W) {
  constexpr int MT = COUT / 16;
  constexpr int CK = 32;
  __shared__ alignas(16) bf16 in_lds[324 * CK];
  __shared__ alignas(16) bf16 w_lds[9 * COUT * CK];
  const int tid = threadIdx.x;
  const int lane = tid & 63;
  const int wid = tid >> 6;
  const int lm = lane & 15;
  const int quad = lane >> 4;
  // perimeter tile mapping (G x G tile grid, H == W)
  const int G = W >> 4;
  int t = blockIdx.x;
  int tx, ty;
  if (t < G) { ty = 0; tx = t; }
  else if (t < 2 * G) { ty = G - 1; tx = t - G; }
  else { int u = t - 2 * G; ty = 1 + (u >> 1); tx = (u & 1) ? (G - 1) : 0; }
  const int x0 = tx * 16, y0 = ty * 16;
  const int b = blockIdx.z;
  const int Hs = H >> 1, Ws = W >> 1;

  float4v acc[MT][4];
#pragma unroll
  for (int mt = 0; mt < MT; ++mt) {
    float4v bv = *(const float4v*)(bias + mt * 16 + quad * 4);
#pragma unroll
    for (int nt = 0; nt < 4; ++nt) acc[mt][nt] = bv;
  }

  for (int c0 = 0; c0 < CIN; c0 += CK) {
    // fused x2 bilinear upsample staging (zero outside image, clamp at edges)
    for (int u = tid; u < 324 * 4; u += 256) {
      int px = u >> 2;
      int seg = u & 3;
      int hy = px / 18, hx = px - hy * 18;
      int gy = y0 - 1 + hy, gx = x0 - 1 + hx;
      uint4 o = make_uint4(0, 0, 0, 0);
      if (gy >= 0 && gy < H && gx >= 0 && gx < W) {
        int ys = (gy >> 1) - ((gy & 1) ? 0 : 1);
        int xs = (gx >> 1) - ((gx & 1) ? 0 : 1);
        float wy = (gy & 1) ? 0.25f : 0.75f;
        float wx = (gx & 1) ? 0.25f : 0.75f;
        int y0c = max(ys, 0), y1c = min(ys + 1, Hs - 1);
        int x0c = max(xs, 0), x1c = min(xs + 1, Ws - 1);
        const bf16* p = in + ((long)b * Hs * Ws) * CIN + c0 + seg * 8;
        union { uint4 v; ushort_t s[8]; } a00, a01, a10, a11, r;
        a00.v = *(const uint4*)(p + ((long)y0c * Ws + x0c) * CIN);
        a01.v = *(const uint4*)(p + ((long)y0c * Ws + x1c) * CIN);
        a10.v = *(const uint4*)(p + ((long)y1c * Ws + x0c) * CIN);
        a11.v = *(const uint4*)(p + ((long)y1c * Ws + x1c) * CIN);
#pragma unroll
        for (int j = 0; j < 8; ++j) {
          float f = (1.0f - wy) * ((1.0f - wx) * bfu2f(a00.s[j]) +
                                   wx * bfu2f(a01.s[j])) +
                    wy * ((1.0f - wx) * bfu2f(a10.s[j]) +
                          wx * bfu2f(a11.s[j]));
          r.s[j] = f2bfu(f);
        }
        o = r.v;
      }
      *(uint4*)&in_lds[px * CK + seg * 8] = o;
    }
    {
      const char* wsrc = (const char*)(wt + (size_t)(c0 >> 5) * 9 * COUT * CK);
      constexpr int WCH = 9 * COUT * CK * 2 / 1024;
      for (int j = wid; j < WCH; j += 4)
        dma16((char*)w_lds + j * 1024, wsrc + j * 1024 + lane * 16);
    }
    __syncthreads();
#pragma unroll
    for (int tap = 0; tap < 9; ++tap) {
      const int r = tap / 3, s = tap - r * 3;
      short8 afrag[MT], bfrag[4];
#pragma unroll
      for (int mt = 0; mt < MT; ++mt)
        afrag[mt] =
            *(const short8*)&w_lds[(tap * COUT + mt * 16 + lm) * CK + quad * 8];
#pragma unroll
      for (int nt = 0; nt < 4; ++nt) {
        int py = 4 * wid + nt;
        bfrag[nt] =
            *(const short8*)&in_lds[((py + r) * 18 + lm + s) * CK + quad * 8];
      }
#pragma unroll
      for (int mt = 0; mt < MT; ++mt)
#pragma unroll
        for (int nt = 0; nt < 4; ++nt)
          acc[mt][nt] = __builtin_amdgcn_mfma_f32_16x16x32_bf16(
              afrag[mt], bfrag[nt], acc[mt][nt], 0, 0, 0);
    }
    __syncthreads();
  }

#pragma unroll
  for (int mt = 0; mt < MT; ++mt)
#pragma unroll
    for (int nt = 0; nt < 4; ++nt) {
      int gy = y0 + 4 * wid + nt;
      int gx = x0 + lm;
      union { uint2 v; ushort_t s[4]; } pk;
#pragma unroll
      for (int r = 0; r < 4; ++r) pk.s[r] = f2bfu(fmaxf(acc[mt][nt][r], 0.0f));
      *(uint2*)&out[(((long)b * H + gy) * W + gx) * COUT + mt * 16 +
                    quad * 4] = pk.v;
    }
}

// ---------------------------------------------------------------------------
// patches: grid_sample bilinear, zeros padding -> out [B,256,3,64,64]
// ---------------------------------------------------------------------------
__global__ __launch_bounds__(256) void patches_k(const float* __restrict__ x,
                                                 const float* __restrict__ def,
                                                 float* __restrict__ out) {
  int i = blockIdx.x * 256 + threadIdx.x;
  int pj = i & 63;
  int t = i >> 6;
  int pi = t & 63;
  t >>= 6;
  int n = t & 255;
  int b = t >> 8;
  if (b >= BATCH) return;
  int hi = n >> 4, wi = n & 15;
  const float* dptr = def + (((long)b * HH + hi * 32) * WW + wi * 32) * 2;
  float cx = dptr[0], cy = dptr[1];
  float pgx = cx + (-1.0f + pj * (2.0f / 63.0f)) * 0.125f;
  float pgy = cy + (-1.0f + pi * (2.0f / 63.0f)) * 0.125f;
  float ix = ((pgx + 1.0f) * 512.0f - 1.0f) * 0.5f;
  float iy = ((pgy + 1.0f) * 512.0f - 1.0f) * 0.5f;
  float fx0 = floorf(ix), fy0 = floorf(iy);
  float wx1 = ix - fx0, wy1 = iy - fy0;
  int x0 = (int)fx0, y0 = (int)fy0;
  int x1 = x0 + 1, y1 = y0 + 1;
  bool vx0 = (x0 >= 0) && (x0 <= 511), vx1 = (x1 >= 0) && (x1 <= 511);
  bool vy0 = (y0 >= 0) && (y0 <= 511), vy1 = (y1 >= 0) && (y1 <= 511);
  int cx0 = min(max(x0, 0), 511), cx1 = min(max(x1, 0), 511);
  int cy0 = min(max(y0, 0), 511), cy1 = min(max(y1, 0), 511);
  float w00 = (1.0f - wx1) * (1.0f - wy1) * ((vx0 && vy0) ? 1.0f : 0.0f);
  float w01 = wx1 * (1.0f - wy1) * ((vx1 && vy0) ? 1.0f : 0.0f);
  float w10 = (1.0f - wx1) * wy1 * ((vx0 && vy1) ? 1.0f : 0.0f);
  float w11 = wx1 * wy1 * ((vx1 && vy1) ? 1.0f : 0.0f);
#pragma unroll
  for (int c = 0; c < 3; ++c) {
    const float* img = x + ((long)b * 3 + c) * (HH * WW);
    float v = img[cy0 * WW + cx0] * w00 + img[cy0 * WW + cx1] * w01 +
              img[cy1 * WW + cx0] * w10 + img[cy1 * WW + cx1] * w11;
    out[(((long)b * 256 + n) * 3 + c) * 4096 + pi * 64 + pj] = v;
  }
}

// ---------------------------------------------------------------------------

extern "C" void kernel_launch(void* const* d_in, const int* in_sizes, int n_in,
                              void* d_out, int out_size, void* d_ws,
                              size_t ws_size, hipStream_t stream) {
  const float* x = (const float*)d_in[0];
  WP wp;
  const float* bs[8];
  for (int i = 0; i < 8; ++i) {
    wp.w[i] = (const float*)d_in[1 + 2 * i];
    bs[i] = (const float*)d_in[2 + 2 * i];
  }
  const float* temp = (const float*)d_in[17];

  float* out = (float*)d_out;
  float* flow = out + 12582912;  // [B,2,512,512] f32
  float* def = out + 14680064;   // [B,512,512,2] f32
  bf16* wT = (bf16*)d_out;       // weight stash; patches_k overwrites LAST

  const size_t bufElems = (size_t)BATCH * 512 * 512 * 32;
  bf16* A = (bf16*)d_ws;
  bf16* Bf = A + bufElems;
  bf16* xp = Bf + bufElems;

  prep_w<<<dim3(576, 10), 256, 0, stream>>>(wp, wT);
  pack_x<<<(BATCH * HH * WW) / 256, 256, 0, stream>>>(x, xp);

  dim3 g512(32, 32, BATCH);
  dim3 g256(16, 16, BATCH);

  // conv0 (tap-packed): xp -> A [512,512,32]
  conv0_k<<<g512, 256, 0, stream>>>(xp, wT + WO_L0, bs[0], A);
  // conv1 + relu + pool: A -> Bf [256,256,32]
  conv_mfma<32, 32, 32, 3>
      <<<g512, 256, 0, stream>>>(A, wT + WO_L1, bs[1], Bf, 512, 512, nullptr, nullptr);
  // conv2: Bf -> A [256,256,64]
  conv_mfma<32, 64, 64, 0>
      <<<g256, 256, 0, stream>>>(Bf, wT + WO_L2, bs[2], A, 256, 256, nullptr, nullptr);
  // conv3 + relu + pool: A -> Bf [128,128,64]
  conv_mfma<64, 64, 64, 3>
      <<<g256, 256, 0, stream>>>(A, wT + WO_L3, bs[3], Bf, 256, 256, nullptr, nullptr);
  // conv4 (phase-decomposed up1): Bf(128² src) -> A [256,256,64]
  conv_up<64, 64><<<dim3(8, 8, BATCH), 256, 0, stream>>>(Bf, wT + WO_L4P, bs[4], A, 256, 256);
  // exact perimeter tiles (60 = 4*16-4)
  conv_edge<64, 64><<<dim3(60, 1, BATCH), 256, 0, stream>>>(Bf, wT + WO_L4U, bs[4], A, 256, 256);
  // conv5: A -> Bf [256,256,32]
  conv_mfma<64, 32, 32, 0>
      <<<g256, 256, 0, stream>>>(A, wT + WO_L5, bs[5], Bf, 256, 256, nullptr, nullptr);
  // conv6 (phase-decomposed up2): Bf(256² src) -> A [512,512,32]
  conv_up<32, 32><<<dim3(16, 16, BATCH), 256, 0, stream>>>(Bf, wT + WO_L6P, bs[6], A, 512, 512);
  // exact perimeter tiles (124 = 4*32-4)
  conv_edge<32, 32><<<dim3(124, 1, BATCH), 256, 0, stream>>>(Bf, wT + WO_L6U, bs[6], A, 512, 512);
  // conv7 + tanh + fused deformed: A -> flow + def
  conv_mfma<32, 16, 2, 2>
      <<<g512, 256, 0, stream>>>(A, wT + WO_L7, bs[7], flow, 512, 512, temp, def);
  // patches (overwrites the wT stash)
  patches_k<<<(BATCH * 256 * 64 * 64) / 256, 256, 0, stream>>>(x, def, out);
}